// Round 1
// baseline (103.452 us; speedup 1.0000x reference)
//
#include <hip/hip_runtime.h>
#include <math.h>

// RoPE: x (B=4, H=32, S=4096, D=128) fp32, interleaved even/odd pairs.
// out[..., 2k]   = cos(a_k) * x[..., 2k]   - sin(a_k) * x[..., 2k+1]
// out[..., 2k+1] = sin(a_k) * x[..., 2k]   + cos(a_k) * x[..., 2k+1]
// a_k = pos[s] * 10000^(-2k/D)
//
// Strategy: memory-bound streaming. One float4 = 2 pairs per thread-iter.
// Each thread owns a fixed (s, d4) and loops over 32 of the 128 bh slices
// (stride S*D elements) -> trig computed once per thread, amortized 32x.
// Every iteration the wave touches a contiguous 1 KiB region (coalesced).

#define S_LEN   4096
#define D_DIM   128
#define BH      128          // B*H = 4*32
#define ROW4    (D_DIM / 4)  // 32 float4 per row
#define NSPLIT  4            // split bh loop across threads
#define BH_PER  (BH / NSPLIT)

__global__ __launch_bounds__(256) void rope_78408922956139_kernel(
    const float4* __restrict__ x,
    const int*    __restrict__ pos,
    float4*       __restrict__ out)
{
    const unsigned t   = blockIdx.x * blockDim.x + threadIdx.x;  // 0 .. S*ROW4*NSPLIT-1
    const unsigned sd  = t & (S_LEN * ROW4 - 1);                 // (s, d4) flat
    const unsigned grp = t >> 17;                                // bh group, S*ROW4 = 2^17
    const unsigned d4  = sd & (ROW4 - 1);
    const unsigned s   = sd >> 5;                                // ROW4 = 32

    const float p = (float)pos[s];

    // pair indices covered by this float4: k0 = 2*d4, k1 = 2*d4 + 1
    const float log_theta = 9.210340371976184f;  // ln(10000)
    const float k0 = 2.0f * (float)d4;
    const float k1 = k0 + 1.0f;
    const float inv0 = __expf(0.0f) * expf(-2.0f * k0 / (float)D_DIM * log_theta);
    const float inv1 = expf(-2.0f * k1 / (float)D_DIM * log_theta);

    float c0, s0v, c1, s1v;
    sincosf(p * inv0, &s0v, &c0);
    sincosf(p * inv1, &s1v, &c1);

    const unsigned stride4 = S_LEN * ROW4;                 // float4 stride per bh slice
    unsigned idx = (grp * BH_PER) * stride4 + sd;

    #pragma unroll 4
    for (int j = 0; j < BH_PER; ++j) {
        float4 v = x[idx];
        float4 o;
        o.x = c0  * v.x - s0v * v.y;
        o.y = s0v * v.x + c0  * v.y;
        o.z = c1  * v.z - s1v * v.w;
        o.w = s1v * v.z + c1  * v.w;
        out[idx] = o;
        idx += stride4;
    }
}

extern "C" void kernel_launch(void* const* d_in, const int* in_sizes, int n_in,
                              void* d_out, int out_size, void* d_ws, size_t ws_size,
                              hipStream_t stream)
{
    const float4* x   = (const float4*)d_in[0];
    const int*    pos = (const int*)d_in[1];
    float4*       out = (float4*)d_out;

    const int total_threads = S_LEN * ROW4 * NSPLIT;  // 524288
    const int block = 256;
    const int grid  = total_threads / block;          // 2048

    hipLaunchKernelGGL(rope_78408922956139_kernel, dim3(grid), dim3(block), 0, stream,
                       x, pos, out);
}

// Round 3
// 95.684 us; speedup vs baseline: 1.0812x; 1.0812x over previous
//
#include <hip/hip_runtime.h>
#include <math.h>

// RoPE: x (B=4, H=32, S=4096, D=128) fp32, interleaved even/odd pairs.
// out[..., 2k]   = cos(a_k) * x[..., 2k] - sin(a_k) * x[..., 2k+1]
// out[..., 2k+1] = sin(a_k) * x[..., 2k] + cos(a_k) * x[..., 2k+1]
// a_k = pos[s] * 10000^(-2k/D)
//
// Memory-bound streaming (536.9 MB total). One float4 = 2 pairs per
// thread-iter. Each thread owns a fixed (s, d4), computes its 2 sincos
// ONCE, then loops over 32 of the 128 bh slices (stride S*D elements).
// Wave accesses stay contiguous/coalesced every iteration.
// R2: nontemporal via clang ext_vector_type (HIP_vector_type rejected by
//     the builtin), unroll 8 for deeper MLP.

#define S_LEN   4096
#define D_DIM   128
#define BH      128          // B*H = 4*32
#define ROW4    (D_DIM / 4)  // 32 float4 per row
#define NSPLIT  4            // split bh loop across threads
#define BH_PER  (BH / NSPLIT)

typedef float f32x4 __attribute__((ext_vector_type(4)));

__global__ __launch_bounds__(256) void rope_78408922956139_kernel(
    const f32x4* __restrict__ x,
    const int*   __restrict__ pos,
    f32x4*       __restrict__ out)
{
    const unsigned t   = blockIdx.x * blockDim.x + threadIdx.x;  // 0 .. S*ROW4*NSPLIT-1
    const unsigned sd  = t & (S_LEN * ROW4 - 1);                 // (s, d4) flat
    const unsigned grp = t >> 17;                                // bh group; S*ROW4 = 2^17
    const unsigned d4  = sd & (ROW4 - 1);
    const unsigned s   = sd >> 5;                                // ROW4 = 32

    const float p = (float)pos[s];

    // pair indices covered by this float4: k0 = 2*d4, k1 = 2*d4 + 1
    const float log_theta = 9.210340371976184f;  // ln(10000)
    const float k0 = 2.0f * (float)d4;
    const float k1 = k0 + 1.0f;
    const float inv0 = expf(-2.0f * k0 / (float)D_DIM * log_theta);
    const float inv1 = expf(-2.0f * k1 / (float)D_DIM * log_theta);

    float c0, s0v, c1, s1v;
    sincosf(p * inv0, &s0v, &c0);
    sincosf(p * inv1, &s1v, &c1);

    const unsigned stride4 = S_LEN * ROW4;                 // f32x4 stride per bh slice
    unsigned idx = (grp * BH_PER) * stride4 + sd;

    #pragma unroll 8
    for (int j = 0; j < BH_PER; ++j) {
        f32x4 v = __builtin_nontemporal_load(&x[idx]);
        f32x4 o;
        o.x = c0  * v.x - s0v * v.y;
        o.y = s0v * v.x + c0  * v.y;
        o.z = c1  * v.z - s1v * v.w;
        o.w = s1v * v.z + c1  * v.w;
        __builtin_nontemporal_store(o, &out[idx]);
        idx += stride4;
    }
}

extern "C" void kernel_launch(void* const* d_in, const int* in_sizes, int n_in,
                              void* d_out, int out_size, void* d_ws, size_t ws_size,
                              hipStream_t stream)
{
    const f32x4* x   = (const f32x4*)d_in[0];
    const int*   pos = (const int*)d_in[1];
    f32x4*       out = (f32x4*)d_out;

    const int total_threads = S_LEN * ROW4 * NSPLIT;  // 524288
    const int block = 256;
    const int grid  = total_threads / block;          // 2048

    hipLaunchKernelGGL(rope_78408922956139_kernel, dim3(grid), dim3(block), 0, stream,
                       x, pos, out);
}

// Round 4
// 94.469 us; speedup vs baseline: 1.0951x; 1.0129x over previous
//
#include <hip/hip_runtime.h>
#include <math.h>

// RoPE: x (B=4, H=32, S=4096, D=128) fp32, interleaved even/odd pairs.
// out[..., 2k]   = cos(a_k) * x[..., 2k] - sin(a_k) * x[..., 2k+1]
// out[..., 2k+1] = sin(a_k) * x[..., 2k] + cos(a_k) * x[..., 2k+1]
// a_k = pos[s] * 10000^(-2k/D)
//
// Memory-bound streaming (536.9 MB total, floor 85.4 us @ 6.29 TB/s).
// One float4 = 2 pairs per thread-iter. Each thread owns a fixed (s, d4),
// computes its 2 sincos ONCE, then loops over 16 of the 128 bh slices
// (stride S*D elements). Wave accesses contiguous/coalesced every iter.
// R2: nontemporal ld/st via ext_vector_type (use-once streams). 103.5->95.7us.
// R3: NSPLIT 4->8 (4096 blocks, 16 blocks/CU -> finer tail), full unroll.

#define S_LEN   4096
#define D_DIM   128
#define BH      128          // B*H = 4*32
#define ROW4    (D_DIM / 4)  // 32 float4 per row
#define NSPLIT  8            // split bh loop across threads
#define BH_PER  (BH / NSPLIT)

typedef float f32x4 __attribute__((ext_vector_type(4)));

__global__ __launch_bounds__(256) void rope_78408922956139_kernel(
    const f32x4* __restrict__ x,
    const int*   __restrict__ pos,
    f32x4*       __restrict__ out)
{
    const unsigned t   = blockIdx.x * blockDim.x + threadIdx.x;  // 0 .. S*ROW4*NSPLIT-1
    const unsigned sd  = t & (S_LEN * ROW4 - 1);                 // (s, d4) flat
    const unsigned grp = t >> 17;                                // bh group; S*ROW4 = 2^17
    const unsigned d4  = sd & (ROW4 - 1);
    const unsigned s   = sd >> 5;                                // ROW4 = 32

    const float p = (float)pos[s];

    // pair indices covered by this float4: k0 = 2*d4, k1 = 2*d4 + 1
    const float log_theta = 9.210340371976184f;  // ln(10000)
    const float k0 = 2.0f * (float)d4;
    const float k1 = k0 + 1.0f;
    const float inv0 = expf(-2.0f * k0 / (float)D_DIM * log_theta);
    const float inv1 = expf(-2.0f * k1 / (float)D_DIM * log_theta);

    float c0, s0v, c1, s1v;
    sincosf(p * inv0, &s0v, &c0);
    sincosf(p * inv1, &s1v, &c1);

    const unsigned stride4 = S_LEN * ROW4;                 // f32x4 stride per bh slice
    unsigned idx = (grp * BH_PER) * stride4 + sd;

    #pragma unroll
    for (int j = 0; j < BH_PER; ++j) {
        f32x4 v = __builtin_nontemporal_load(&x[idx]);
        f32x4 o;
        o.x = c0  * v.x - s0v * v.y;
        o.y = s0v * v.x + c0  * v.y;
        o.z = c1  * v.z - s1v * v.w;
        o.w = s1v * v.z + c1  * v.w;
        __builtin_nontemporal_store(o, &out[idx]);
        idx += stride4;
    }
}

extern "C" void kernel_launch(void* const* d_in, const int* in_sizes, int n_in,
                              void* d_out, int out_size, void* d_ws, size_t ws_size,
                              hipStream_t stream)
{
    const f32x4* x   = (const f32x4*)d_in[0];
    const int*   pos = (const int*)d_in[1];
    f32x4*       out = (f32x4*)d_out;

    const int total_threads = S_LEN * ROW4 * NSPLIT;  // 1048576
    const int block = 256;
    const int grid  = total_threads / block;          // 4096

    hipLaunchKernelGGL(rope_78408922956139_kernel, dim3(grid), dim3(block), 0, stream,
                       x, pos, out);
}